// Round 1
// baseline (1149.602 us; speedup 1.0000x reference)
//
#include <hip/hip_runtime.h>
#include <math.h>

#define BDIM 32
#define CDIM 256
#define HDIM 128
#define WDIM 128
#define HW   (HDIM * WDIM)   // 16384
#define HW4  (HW / 4)        // 4096
#define CSPLIT 8
#define CCHUNK (CDIM / CSPLIT)  // 32

// ---------------------------------------------------------------------------
// Kernel 1: channel-wise mean & max of y -> avgbuf, maxbuf  ([B*HW] floats)
// One thread per (b, 4 consecutive w). Wave reads 1 KiB contiguous per c-step.
// 4 independent sum accumulators so the 4 loads/iter pipeline freely.
// ---------------------------------------------------------------------------
__global__ __launch_bounds__(256) void reduce_kernel(
    const float4* __restrict__ y,
    float4* __restrict__ avgb,
    float4* __restrict__ maxb)
{
    const int idx = blockIdx.x * 256 + threadIdx.x;   // [0, B*HW4)
    const int b   = idx >> 12;                        // / HW4
    const int hw4 = idx & (HW4 - 1);
    const float4* yp = y + (size_t)(b * CDIM) * HW4 + hw4;

    float4 s0 = {0.f, 0.f, 0.f, 0.f};
    float4 s1 = {0.f, 0.f, 0.f, 0.f};
    float4 s2 = {0.f, 0.f, 0.f, 0.f};
    float4 s3 = {0.f, 0.f, 0.f, 0.f};
    float4 m  = {-INFINITY, -INFINITY, -INFINITY, -INFINITY};

    #pragma unroll 4
    for (int c = 0; c < CDIM; c += 4) {
        float4 v0 = yp[(size_t)(c + 0) * HW4];
        float4 v1 = yp[(size_t)(c + 1) * HW4];
        float4 v2 = yp[(size_t)(c + 2) * HW4];
        float4 v3 = yp[(size_t)(c + 3) * HW4];

        s0.x += v0.x; s0.y += v0.y; s0.z += v0.z; s0.w += v0.w;
        s1.x += v1.x; s1.y += v1.y; s1.z += v1.z; s1.w += v1.w;
        s2.x += v2.x; s2.y += v2.y; s2.z += v2.z; s2.w += v2.w;
        s3.x += v3.x; s3.y += v3.y; s3.z += v3.z; s3.w += v3.w;

        m.x = fmaxf(m.x, fmaxf(fmaxf(v0.x, v1.x), fmaxf(v2.x, v3.x)));
        m.y = fmaxf(m.y, fmaxf(fmaxf(v0.y, v1.y), fmaxf(v2.y, v3.y)));
        m.z = fmaxf(m.z, fmaxf(fmaxf(v0.z, v1.z), fmaxf(v2.z, v3.z)));
        m.w = fmaxf(m.w, fmaxf(fmaxf(v0.w, v1.w), fmaxf(v2.w, v3.w)));
    }

    const float inv = 1.0f / (float)CDIM;
    float4 a;
    a.x = (s0.x + s1.x + s2.x + s3.x) * inv;
    a.y = (s0.y + s1.y + s2.y + s3.y) * inv;
    a.z = (s0.z + s1.z + s2.z + s3.z) * inv;
    a.w = (s0.w + s1.w + s2.w + s3.w) * inv;

    avgb[idx] = a;
    maxb[idx] = m;
}

// ---------------------------------------------------------------------------
// Kernel 2: gate = sigmoid(conv3x3([avg;max], w))   -> gate [B*HW] floats
// Tiny: inputs are 4 MiB (L2-resident). One thread per 4 outputs in a row.
// JAX conv_general_dilated = cross-correlation (no kernel flip).
// ---------------------------------------------------------------------------
__global__ __launch_bounds__(256) void gate_kernel(
    const float* __restrict__ avgb,
    const float* __restrict__ maxb,
    const float* __restrict__ wgt,    // [1,2,3,3]: wgt[0..8]=avg-ch, wgt[9..17]=max-ch
    float4* __restrict__ gate)
{
    const int idx = blockIdx.x * 256 + threadIdx.x;   // [0, B*HW4)
    const int b   = idx >> 12;
    const int hw4 = idx & (HW4 - 1);
    const int hw  = hw4 << 2;
    const int h   = hw >> 7;          // / W
    const int w0  = hw & (WDIM - 1);

    float wa[9], wm[9];
    #pragma unroll
    for (int i = 0; i < 9; ++i) { wa[i] = wgt[i]; wm[i] = wgt[9 + i]; }

    const float* ab = avgb + b * HW;
    const float* mb = maxb + b * HW;

    float g0 = 0.f, g1 = 0.f, g2 = 0.f, g3 = 0.f;

    #pragma unroll
    for (int kh = 0; kh < 3; ++kh) {
        const int r = h - 1 + kh;
        if (r < 0 || r >= HDIM) continue;   // zero padding: contributes 0
        const float* ar = ab + r * WDIM + w0;
        const float* mr = mb + r * WDIM + w0;
        float A[6], M[6];
        #pragma unroll
        for (int j = 0; j < 6; ++j) {
            const int col = w0 + j - 1;
            const bool v = (col >= 0) && (col < WDIM);
            A[j] = v ? ar[j - 1] : 0.f;
            M[j] = v ? mr[j - 1] : 0.f;
        }
        #pragma unroll
        for (int kw = 0; kw < 3; ++kw) {
            const float fa = wa[kh * 3 + kw];
            const float fm = wm[kh * 3 + kw];
            g0 += A[0 + kw] * fa + M[0 + kw] * fm;
            g1 += A[1 + kw] * fa + M[1 + kw] * fm;
            g2 += A[2 + kw] * fa + M[2 + kw] * fm;
            g3 += A[3 + kw] * fa + M[3 + kw] * fm;
        }
    }

    float4 o;
    o.x = 1.0f / (1.0f + __expf(-g0));
    o.y = 1.0f / (1.0f + __expf(-g1));
    o.z = 1.0f / (1.0f + __expf(-g2));
    o.w = 1.0f / (1.0f + __expf(-g3));
    gate[idx] = o;
}

// ---------------------------------------------------------------------------
// Kernel 3: out[b,c,h,w] = x[b,c,h,w] * gate[b,h,w]
// gridDim.x over (b,hw4), gridDim.y = channel split (8 groups of 32 channels).
// Gate float4 hoisted to a register before the channel loop.
// ---------------------------------------------------------------------------
__global__ __launch_bounds__(256) void apply_kernel(
    const float4* __restrict__ x,
    const float4* __restrict__ gate,
    float4* __restrict__ out)
{
    const int idx = blockIdx.x * 256 + threadIdx.x;   // [0, B*HW4)
    const int b   = idx >> 12;
    const int hw4 = idx & (HW4 - 1);

    const float4 g = gate[idx];

    const int c0 = blockIdx.y * CCHUNK;
    const size_t base = (size_t)(b * CDIM + c0) * HW4 + hw4;
    const float4* xp = x + base;
    float4*       op = out + base;

    #pragma unroll 4
    for (int c = 0; c < CCHUNK; ++c) {
        float4 v = xp[(size_t)c * HW4];
        v.x *= g.x; v.y *= g.y; v.z *= g.z; v.w *= g.w;
        op[(size_t)c * HW4] = v;
    }
}

extern "C" void kernel_launch(void* const* d_in, const int* in_sizes, int n_in,
                              void* d_out, int out_size, void* d_ws, size_t ws_size,
                              hipStream_t stream)
{
    const float* x      = (const float*)d_in[0];
    const float* y      = (const float*)d_in[1];
    const float* conv_w = (const float*)d_in[2];
    float*       out    = (float*)d_out;

    // workspace layout: avg [B*HW] | max [B*HW] | gate [B*HW]   (6 MiB total)
    float* avgb = (float*)d_ws;
    float* maxb = avgb + (size_t)BDIM * HW;
    float* gate = maxb + (size_t)BDIM * HW;

    const int nPos4   = BDIM * HW4;           // 131072 threads
    const int nBlocks = nPos4 / 256;          // 512

    reduce_kernel<<<nBlocks, 256, 0, stream>>>(
        (const float4*)y, (float4*)avgb, (float4*)maxb);

    gate_kernel<<<nBlocks, 256, 0, stream>>>(
        avgb, maxb, conv_w, (float4*)gate);

    dim3 grid3(nBlocks, CSPLIT);
    apply_kernel<<<grid3, 256, 0, stream>>>(
        (const float4*)x, (const float4*)gate, (float4*)out);
}